// Round 2
// baseline (98.231 us; speedup 1.0000x reference)
//
#include <hip/hip_runtime.h>

// DCT2D_Layer: 8x8 block DCT-II (norm=None) + zigzag reorder.
// img [16,3,512,512] f32 -> out [16, 3*64, 64, 64] f32
// v6: 2 threads per 8x8 block (row-split). Lanes 0-31 hold rows 0-3,
//     lanes 32-63 hold rows 4-7 of the same 32 blocks. 6144 waves
//     (24/CU, 2x v5) for latency hiding; no LDS, no barriers.
//     Column DCT first stage (row_i +/- row_{7-i}) via 4 shfl_xor(32)
//     per column; low half then computes even-u coefficients, high half
//     odd-u. 128B-contiguous nontemporal stores (granularity proven
//     non-critical by v4==v5).

// 2*cos(m*pi/16)
#define K1 1.9615705608064609f
#define K2 1.8477590650225735f
#define K3 1.6629392246050905f
#define K4 1.4142135623730951f
#define K5 1.1111404660392044f
#define K6 0.7653668647301796f
#define K7 0.3901806440322565f

// Unnormalized DCT-II, factor 2: y[k] = 2*sum_n x[n] cos(pi*(2n+1)k/16)
#define DCT8(x0,x1,x2,x3,x4,x5,x6,x7, y0,y1,y2,y3,y4,y5,y6,y7) do {        \
    float s0=(x0)+(x7), s1=(x1)+(x6), s2=(x2)+(x5), s3=(x3)+(x4);          \
    float d0=(x0)-(x7), d1=(x1)-(x6), d2=(x2)-(x5), d3=(x3)-(x4);          \
    float e0=s0+s3, e1=s1+s2, o0=s0-s3, o1=s1-s2;                          \
    y0 = 2.0f*(e0+e1);                                                     \
    y4 = K4*(e0-e1);                                                       \
    y2 = K2*o0 + K6*o1;                                                    \
    y6 = K6*o0 - K2*o1;                                                    \
    y1 = K1*d0 + K3*d1 + K5*d2 + K7*d3;                                    \
    y3 = K3*d0 - K7*d1 - K1*d2 - K5*d3;                                    \
    y5 = K5*d0 - K1*d1 + K7*d2 + K3*d3;                                    \
    y7 = K7*d0 - K5*d1 + K3*d2 - K1*d3;                                    \
} while (0)

// Hoisted load of local row r (two float4 = 32B of this block row).
#define LOADROW(r)                                                          \
    const float4 L##r##a = *reinterpret_cast<const float4*>(src + (r)*512); \
    const float4 L##r##b = *reinterpret_cast<const float4*>(src + (r)*512 + 4);

// Row-pass DCT on the already-loaded local row r -> t[r][0..7].
#define ROWDCT(r)                                                          \
    DCT8(L##r##a.x,L##r##a.y,L##r##a.z,L##r##a.w,                          \
         L##r##b.x,L##r##b.y,L##r##b.z,L##r##b.w,                          \
         t##r##0,t##r##1,t##r##2,t##r##3,t##r##4,t##r##5,t##r##6,t##r##7);

// Column pass for column c. Exchange the 4 partner values across the
// lane<32 / lane>=32 split, then:
//   low half  (rows 0-3): s_i = row_i + row_{7-i} -> even outputs y0,y2,y4,y6
//   high half (rows 4-7): d_i = row_i - row_{7-i} -> odd  outputs y1,y3,y5,y7
// pa* = zigzag planes for u=0,2,4,6 ; pb* = planes for u=1,3,5,7.
#define COLP(c, pa0,pa1,pa2,pa3, pb0,pb1,pb2,pb3) do {                     \
    const float o0f = __shfl_xor(t0##c, 32);                               \
    const float o1f = __shfl_xor(t1##c, 32);                               \
    const float o2f = __shfl_xor(t2##c, 32);                               \
    const float o3f = __shfl_xor(t3##c, 32);                               \
    if (lane < 32) {                                                       \
        float s0 = t0##c + o3f, s1 = t1##c + o2f;                          \
        float s2 = t2##c + o1f, s3 = t3##c + o0f;                          \
        float e0 = s0+s3, e1 = s1+s2, q0 = s0-s3, q1 = s1-s2;              \
        __builtin_nontemporal_store(2.0f*(e0+e1), dst + (size_t)(pa0)*4096); \
        __builtin_nontemporal_store(K2*q0+K6*q1,  dst + (size_t)(pa1)*4096); \
        __builtin_nontemporal_store(K4*(e0-e1),   dst + (size_t)(pa2)*4096); \
        __builtin_nontemporal_store(K6*q0-K2*q1,  dst + (size_t)(pa3)*4096); \
    } else {                                                               \
        float d0 = o0f - t3##c, d1 = o1f - t2##c;                          \
        float d2 = o2f - t1##c, d3 = o3f - t0##c;                          \
        __builtin_nontemporal_store(K1*d0+K3*d1+K5*d2+K7*d3, dst + (size_t)(pb0)*4096); \
        __builtin_nontemporal_store(K3*d0-K7*d1-K1*d2-K5*d3, dst + (size_t)(pb1)*4096); \
        __builtin_nontemporal_store(K5*d0-K1*d1+K7*d2+K3*d3, dst + (size_t)(pb2)*4096); \
        __builtin_nontemporal_store(K7*d0-K5*d1+K3*d2-K1*d3, dst + (size_t)(pb3)*4096); \
    }                                                                      \
} while (0)

__global__ __launch_bounds__(256) void dct2d_zigzag_kernel(
    const float* __restrict__ img, float* __restrict__ out)
{
    const int gid  = blockIdx.x * 256 + threadIdx.x;  // 0..393215
    const int lane = gid & 63;
    const int wid  = gid >> 6;          // 0..6143 : one wave = 32 blocks
    const int hr   = wid & 1;           // which half of the 64-block row
    const int bi   = (wid >> 1) & 63;   // block row
    const int bc   = wid >> 7;          // b*3 + ch, 0..47
    const int part = lane >> 5;         // 0: rows 0-3, 1: rows 4-7
    const int bj   = hr * 32 + (lane & 31);  // block col

    // Input: img[bc, bi*8 + part*4 + r, bj*8 + x]; channel plane = 512*512
    const float* __restrict__ src =
        img + (size_t)bc * 262144 + (size_t)bi * 4096
            + (size_t)part * 2048 + (size_t)bj * 8;

    // Output: out[bc*64 + p, bi, bj]; plane = 64*64 = 4096 floats.
    float* __restrict__ dst =
        out + (size_t)bc * 262144 + (size_t)bi * 64 + bj;

    // 8 hoisted global loads: 8KB in flight per wave.
    LOADROW(0) LOADROW(1) LOADROW(2) LOADROW(3)

    float t00,t01,t02,t03,t04,t05,t06,t07;
    float t10,t11,t12,t13,t14,t15,t16,t17;
    float t20,t21,t22,t23,t24,t25,t26,t27;
    float t30,t31,t32,t33,t34,t35,t36,t37;

    ROWDCT(0) ROWDCT(1) ROWDCT(2) ROWDCT(3)

    // Zigzag planes per column c: pa = INVZZ[{0,2,4,6}*8+c], pb = INVZZ[{1,3,5,7}*8+c]
    COLP(0,  0,  3, 10, 21,   2,  9, 20, 35);
    COLP(1,  1,  8, 19, 34,   4, 11, 22, 36);
    COLP(2,  5, 12, 23, 37,   7, 18, 33, 48);
    COLP(3,  6, 17, 32, 47,  13, 24, 38, 49);
    COLP(4, 14, 25, 39, 50,  16, 31, 46, 57);
    COLP(5, 15, 30, 45, 56,  26, 40, 51, 58);
    COLP(6, 27, 41, 52, 59,  29, 44, 55, 62);
    COLP(7, 28, 43, 54, 61,  42, 53, 60, 63);
}

extern "C" void kernel_launch(void* const* d_in, const int* in_sizes, int n_in,
                              void* d_out, int out_size, void* d_ws, size_t ws_size,
                              hipStream_t stream)
{
    const float* img = (const float*)d_in[0];
    float* out = (float*)d_out;
    // 393216 threads; 256/block -> 1536 workgroups (6 per CU, 24 waves/CU)
    dct2d_zigzag_kernel<<<1536, 256, 0, stream>>>(img, out);
}